// Round 1
// baseline (640.779 us; speedup 1.0000x reference)
//
#include <hip/hip_runtime.h>

typedef unsigned short u16;
typedef float f32x4 __attribute__((ext_vector_type(4)));
typedef __bf16 bf16x8 __attribute__((ext_vector_type(8)));
typedef u16 u16x4 __attribute__((ext_vector_type(4)));
typedef u16 u16x8 __attribute__((ext_vector_type(8)));

__device__ __forceinline__ float bf2f(u16 u) {
    unsigned int x = ((unsigned int)u) << 16;
    return __builtin_bit_cast(float, x);
}
__device__ __forceinline__ u16 f2bf(float f) {
    unsigned int x = __builtin_bit_cast(unsigned int, f);
    x += 0x7fffu + ((x >> 16) & 1u);   // RNE
    return (u16)(x >> 16);
}

#define GLD16(gp, lp)                                                          \
    __builtin_amdgcn_global_load_lds(                                          \
        (const __attribute__((address_space(1))) void*)(gp),                   \
        (__attribute__((address_space(3))) void*)(lp), 16, 0, 0)

// ---------------------------------------------------------------------------
// prep kernels
// ---------------------------------------------------------------------------
__global__ void f32_to_bf16_k(const float* __restrict__ in, u16* __restrict__ out, long n4) {
    long i = (long)blockIdx.x * 256 + threadIdx.x;
    if (i >= n4) return;
    f32x4 v = *reinterpret_cast<const f32x4*>(in + i * 4);
    u16x4 o;
    o[0] = f2bf(v[0]); o[1] = f2bf(v[1]); o[2] = f2bf(v[2]); o[3] = f2bf(v[3]);
    *reinterpret_cast<u16x4*>(out + i * 4) = o;
}

// in fp32 [R][C] -> out bf16 [C][R]
__global__ void transpose_f32_bf16(const float* __restrict__ in, u16* __restrict__ out,
                                   int R, int C) {
    __shared__ float tile[32][33];
    const int bx = blockIdx.x * 32;  // C dim
    const int by = blockIdx.y * 32;  // R dim
    const int tx = threadIdx.x;      // 0..31
    const int ty0 = threadIdx.y;     // 0..7
    #pragma unroll
    for (int ty = ty0; ty < 32; ty += 8)
        tile[ty][tx] = in[(long)(by + ty) * C + bx + tx];
    __syncthreads();
    #pragma unroll
    for (int ty = ty0; ty < 32; ty += 8)
        out[(long)(bx + ty) * R + by + tx] = f2bf(tile[tx][ty]);
}

// H[B][32] = relu(P[B][8] @ W[8][32] + b[32]), bf16 out
__global__ void hyper_h(const float* __restrict__ P, const float* __restrict__ W,
                        const float* __restrict__ b, u16* __restrict__ H, int B_) {
    const int idx = blockIdx.x * 256 + threadIdx.x;
    const int s = idx >> 5, c = idx & 31;
    if (s >= B_) return;
    float acc = b[c];
    #pragma unroll
    for (int k = 0; k < 8; ++k) acc += P[s * 8 + k] * W[k * 32 + c];
    H[idx] = f2bf(fmaxf(acc, 0.f));
}

// ---------------------------------------------------------------------------
// GEMM: C[M][N] = A[M][K] @ BT[N][K]^T + bias, A/BT bf16, out bf16 or fp32
// 128x128 tile, BK=64, 4 waves (2x2), 16x16x32 bf16 MFMA, global_load_lds w16
// ---------------------------------------------------------------------------
template <int OUT_BF16>
__global__ __launch_bounds__(256, 2) void gemm_bt(
    const u16* __restrict__ A, const u16* __restrict__ BT,
    const float* __restrict__ bias, u16* __restrict__ Cb, float* __restrict__ Cf,
    int M, int N, int K) {
    __shared__ __align__(16) u16 As[128 * 64];
    __shared__ __align__(16) u16 Bs[128 * 64];
    const int tid = threadIdx.x;
    const int lane = tid & 63;
    const int wave = tid >> 6;
    const int wr = wave >> 1, wc = wave & 1;
    const long row0 = (long)blockIdx.x * 128;
    const long col0 = (long)blockIdx.y * 128;

    const int srow = tid >> 3;        // 0..31
    const int scol = (tid & 7) * 8;   // 0..56
    const u16* Ag = A + (row0 + srow) * (long)K + scol;
    const u16* Bg = BT + (col0 + srow) * (long)K + scol;
    u16* AsW = As + (size_t)(wave * 64) * 8;
    u16* BsW = Bs + (size_t)(wave * 64) * 8;

    f32x4 acc[4][4] = {};

    for (int k0 = 0; k0 < K; k0 += 64) {
        #pragma unroll
        for (int i = 0; i < 4; ++i) {
            GLD16(Ag + (long)i * 32 * K + k0, AsW + i * 256 * 8);
            GLD16(Bg + (long)i * 32 * K + k0, BsW + i * 256 * 8);
        }
        __syncthreads();
        #pragma unroll
        for (int kk = 0; kk < 2; ++kk) {
            bf16x8 af[4], bfr[4];
            #pragma unroll
            for (int m = 0; m < 4; ++m)
                af[m] = *reinterpret_cast<const bf16x8*>(
                    As + (wr * 64 + m * 16 + (lane & 15)) * 64 + kk * 32 + (lane >> 4) * 8);
            #pragma unroll
            for (int n = 0; n < 4; ++n)
                bfr[n] = *reinterpret_cast<const bf16x8*>(
                    Bs + (wc * 64 + n * 16 + (lane & 15)) * 64 + kk * 32 + (lane >> 4) * 8);
            #pragma unroll
            for (int m = 0; m < 4; ++m)
                #pragma unroll
                for (int n = 0; n < 4; ++n)
                    acc[m][n] = __builtin_amdgcn_mfma_f32_16x16x32_bf16(af[m], bfr[n],
                                                                        acc[m][n], 0, 0, 0);
        }
        __syncthreads();
    }

    #pragma unroll
    for (int n = 0; n < 4; ++n) {
        const long col = col0 + wc * 64 + n * 16 + (lane & 15);
        const float bv = bias[col];
        #pragma unroll
        for (int m = 0; m < 4; ++m) {
            const long rowb = row0 + wr * 64 + m * 16 + ((lane >> 4) * 4);
            #pragma unroll
            for (int r = 0; r < 4; ++r) {
                const float v = acc[m][n][r] + bv;
                if (OUT_BF16) Cb[(rowb + r) * (long)N + col] = f2bf(v);
                else          Cf[(rowb + r) * (long)N + col] = v;
            }
        }
    }
}

// ---------------------------------------------------------------------------
// GroupNorm (n_group=1) + per-sample hypernet affine + ReLU, in place on Y.
// w[r][c] = H[r][:] @ W2[:,c] + b2[c] computed via MFMA (K=32 exactly).
// Block: 256 threads / 4 waves, 32 rows per block, channel chunks of 128.
// ---------------------------------------------------------------------------
template <int C>
__global__ __launch_bounds__(256, 2) void gn_affine(
    u16* __restrict__ Y,
    const u16* __restrict__ Hw, const u16* __restrict__ Hb,
    const u16* __restrict__ WwT, const u16* __restrict__ WbT,
    const float* __restrict__ bw, const float* __restrict__ bb) {
    const int tid = threadIdx.x;
    const int lane = tid & 63;
    const int wave = tid >> 6;
    const long r0 = (long)blockIdx.x * 32;
    __shared__ float mean_l[32], rs_l[32];
    __shared__ __align__(16) float wt[32][132];
    __shared__ __align__(16) float btl[32][132];

    const int row = tid >> 3, sub = tid & 7;

    // ---- stats ----
    {
        float s = 0.f, ss = 0.f;
        const u16* yr = Y + (r0 + row) * (long)C;
        for (int c = sub * 16; c < C; c += 128) {
            u16x8 v0 = *reinterpret_cast<const u16x8*>(yr + c);
            u16x8 v1 = *reinterpret_cast<const u16x8*>(yr + c + 8);
            #pragma unroll
            for (int j = 0; j < 8; ++j) {
                float f0 = bf2f(v0[j]), f1 = bf2f(v1[j]);
                s += f0 + f1;
                ss += f0 * f0 + f1 * f1;
            }
        }
        s  += __shfl_xor(s, 1);  s  += __shfl_xor(s, 2);  s  += __shfl_xor(s, 4);
        ss += __shfl_xor(ss, 1); ss += __shfl_xor(ss, 2); ss += __shfl_xor(ss, 4);
        if (sub == 0) {
            float m = s / (float)C;
            float var = fmaxf(ss / (float)C - m * m, 0.f);
            mean_l[row] = m;
            rs_l[row] = rsqrtf(var + 1e-5f);
        }
    }
    __syncthreads();

    // wave (mm, npair): mm = row-subtile, npair selects 4 of 8 col-subtiles
    const int mm = wave & 1;
    const int npair = wave >> 1;
    const bf16x8 ha = *reinterpret_cast<const bf16x8*>(
        Hw + (r0 + mm * 16 + (lane & 15)) * 32 + (lane >> 4) * 8);
    const bf16x8 hbf = *reinterpret_cast<const bf16x8*>(
        Hb + (r0 + mm * 16 + (lane & 15)) * 32 + (lane >> 4) * 8);

    for (int c0 = 0; c0 < C; c0 += 128) {
        #pragma unroll
        for (int j = 0; j < 4; ++j) {
            const int n = npair * 4 + j;
            const int cl = c0 + n * 16 + (lane & 15);
            const bf16x8 wv = *reinterpret_cast<const bf16x8*>(WwT + (long)cl * 32 + (lane >> 4) * 8);
            const bf16x8 bv = *reinterpret_cast<const bf16x8*>(WbT + (long)cl * 32 + (lane >> 4) * 8);
            f32x4 z = {0.f, 0.f, 0.f, 0.f};
            f32x4 wa = __builtin_amdgcn_mfma_f32_16x16x32_bf16(ha, wv, z, 0, 0, 0);
            f32x4 ba = __builtin_amdgcn_mfma_f32_16x16x32_bf16(hbf, bv, z, 0, 0, 0);
            const float bwv = bw[cl], bbv = bb[cl];
            const int ncol = n * 16 + (lane & 15);
            #pragma unroll
            for (int r = 0; r < 4; ++r) {
                const int rl = mm * 16 + (lane >> 4) * 4 + r;
                wt[rl][ncol]  = wa[r] + bwv;
                btl[rl][ncol] = ba[r] + bbv;
            }
        }
        __syncthreads();
        {
            const long base = (r0 + row) * (long)C + c0 + sub * 16;
            u16x8 v0 = *reinterpret_cast<const u16x8*>(Y + base);
            u16x8 v1 = *reinterpret_cast<const u16x8*>(Y + base + 8);
            const float mu = mean_l[row], rs = rs_l[row];
            u16x8 o0, o1;
            #pragma unroll
            for (int j = 0; j < 8; ++j) {
                float f = (bf2f(v0[j]) - mu) * rs;
                f = f * wt[row][sub * 16 + j] + btl[row][sub * 16 + j];
                o0[j] = f2bf(fmaxf(f, 0.f));
                float g = (bf2f(v1[j]) - mu) * rs;
                g = g * wt[row][sub * 16 + 8 + j] + btl[row][sub * 16 + 8 + j];
                o1[j] = f2bf(fmaxf(g, 0.f));
            }
            *reinterpret_cast<u16x8*>(Y + base) = o0;
            *reinterpret_cast<u16x8*>(Y + base + 8) = o1;
        }
        __syncthreads();
    }
}

// ---------------------------------------------------------------------------
// log_softmax over rows of 256, one wave per row
// ---------------------------------------------------------------------------
__global__ __launch_bounds__(256) void logsoftmax256(const float* __restrict__ X,
                                                     float* __restrict__ O) {
    const int wave = threadIdx.x >> 6, lane = threadIdx.x & 63;
    const long row = (long)blockIdx.x * 4 + wave;
    const float* x = X + row * 256 + lane * 4;
    f32x4 v = *reinterpret_cast<const f32x4*>(x);
    float mx = fmaxf(fmaxf(v[0], v[1]), fmaxf(v[2], v[3]));
    #pragma unroll
    for (int d = 1; d < 64; d <<= 1) mx = fmaxf(mx, __shfl_xor(mx, d));
    float s = 0.f;
    #pragma unroll
    for (int j = 0; j < 4; ++j) s += __expf(v[j] - mx);
    #pragma unroll
    for (int d = 1; d < 64; d <<= 1) s += __shfl_xor(s, d);
    const float lse = mx + logf(s);
    f32x4 o;
    #pragma unroll
    for (int j = 0; j < 4; ++j) o[j] = v[j] - lse;
    *reinterpret_cast<f32x4*>(O + row * 256 + lane * 4) = o;
}

// ---------------------------------------------------------------------------
extern "C" void kernel_launch(void* const* d_in, const int* in_sizes, int n_in,
                              void* d_out, int out_size, void* d_ws, size_t ws_size,
                              hipStream_t stream) {
    const float* x_feature = (const float*)d_in[0];
    const float* x_param   = (const float*)d_in[1];
    const float* hw1_1_w = (const float*)d_in[2];
    const float* hw1_1_b = (const float*)d_in[3];
    const float* hw1_2_w = (const float*)d_in[4];
    const float* hw1_2_b = (const float*)d_in[5];
    const float* hb1_1_w = (const float*)d_in[6];
    const float* hb1_1_b = (const float*)d_in[7];
    const float* hb1_2_w = (const float*)d_in[8];
    const float* hb1_2_b = (const float*)d_in[9];
    const float* hw2_1_w = (const float*)d_in[10];
    const float* hw2_1_b = (const float*)d_in[11];
    const float* hw2_2_w = (const float*)d_in[12];
    const float* hw2_2_b = (const float*)d_in[13];
    const float* hb2_1_w = (const float*)d_in[14];
    const float* hb2_1_b = (const float*)d_in[15];
    const float* hb2_2_w = (const float*)d_in[16];
    const float* hb2_2_b = (const float*)d_in[17];
    const float* l1_w = (const float*)d_in[18];
    const float* l1_b = (const float*)d_in[19];
    const float* l2_w = (const float*)d_in[20];
    const float* l2_b = (const float*)d_in[21];
    const float* l3_w = (const float*)d_in[22];
    const float* l3_b = (const float*)d_in[23];

    const int B = in_sizes[0] / 512;   // 32768
    constexpr int CIN = 512, C1 = 2048, C2 = 1024, COUT = 256;

    char* p = (char*)d_ws;
    auto carve = [&](size_t bytes) {
        char* q = p;
        p += (bytes + 255) & ~(size_t)255;
        return q;
    };
    u16* xb    = (u16*)carve((size_t)B * CIN * 2);
    u16* y1    = (u16*)carve((size_t)B * C1 * 2);
    u16* y2    = (u16*)carve((size_t)B * C2 * 2);
    u16* w1T   = (u16*)carve((size_t)C1 * CIN * 2);
    u16* w2T   = (u16*)carve((size_t)C2 * C1 * 2);
    u16* w3T   = (u16*)carve((size_t)COUT * C2 * 2);
    u16* hw12T = (u16*)carve((size_t)C1 * 32 * 2);
    u16* hb12T = (u16*)carve((size_t)C1 * 32 * 2);
    u16* hw22T = (u16*)carve((size_t)C2 * 32 * 2);
    u16* hb22T = (u16*)carve((size_t)C2 * 32 * 2);
    u16* Hw1   = (u16*)carve((size_t)B * 32 * 2);
    u16* Hb1   = (u16*)carve((size_t)B * 32 * 2);
    u16* Hw2   = (u16*)carve((size_t)B * 32 * 2);
    u16* Hb2   = (u16*)carve((size_t)B * 32 * 2);
    float* logits = (float*)y1;   // y1 is dead by the time logits are written

    // ---- prep ----
    f32_to_bf16_k<<<(B * CIN / 4 + 255) / 256, 256, 0, stream>>>(x_feature, xb, (long)B * CIN / 4);
    dim3 tb(32, 8);
    transpose_f32_bf16<<<dim3(C1 / 32, CIN / 32), tb, 0, stream>>>(l1_w, w1T, CIN, C1);
    transpose_f32_bf16<<<dim3(C2 / 32, C1 / 32), tb, 0, stream>>>(l2_w, w2T, C1, C2);
    transpose_f32_bf16<<<dim3(COUT / 32, C2 / 32), tb, 0, stream>>>(l3_w, w3T, C2, COUT);
    transpose_f32_bf16<<<dim3(C1 / 32, 1), tb, 0, stream>>>(hw1_2_w, hw12T, 32, C1);
    transpose_f32_bf16<<<dim3(C1 / 32, 1), tb, 0, stream>>>(hb1_2_w, hb12T, 32, C1);
    transpose_f32_bf16<<<dim3(C2 / 32, 1), tb, 0, stream>>>(hw2_2_w, hw22T, 32, C2);
    transpose_f32_bf16<<<dim3(C2 / 32, 1), tb, 0, stream>>>(hb2_2_w, hb22T, 32, C2);
    hyper_h<<<B * 32 / 256, 256, 0, stream>>>(x_param, hw1_1_w, hw1_1_b, Hw1, B);
    hyper_h<<<B * 32 / 256, 256, 0, stream>>>(x_param, hb1_1_w, hb1_1_b, Hb1, B);
    hyper_h<<<B * 32 / 256, 256, 0, stream>>>(x_param, hw2_1_w, hw2_1_b, Hw2, B);
    hyper_h<<<B * 32 / 256, 256, 0, stream>>>(x_param, hb2_1_w, hb2_1_b, Hb2, B);

    // ---- main pipeline ----
    gemm_bt<1><<<dim3(B / 128, C1 / 128), 256, 0, stream>>>(xb, w1T, l1_b, y1, nullptr, B, C1, CIN);
    gn_affine<C1><<<B / 32, 256, 0, stream>>>(y1, Hw1, Hb1, hw12T, hb12T, hw1_2_b, hb1_2_b);
    gemm_bt<1><<<dim3(B / 128, C2 / 128), 256, 0, stream>>>(y1, w2T, l2_b, y2, nullptr, B, C2, C1);
    gn_affine<C2><<<B / 32, 256, 0, stream>>>(y2, Hw2, Hb2, hw22T, hb22T, hw2_2_b, hb2_2_b);
    gemm_bt<0><<<dim3(B / 128, COUT / 128), 256, 0, stream>>>(y2, w3T, l3_b, nullptr, logits, B, COUT, C2);
    logsoftmax256<<<B / 4, 256, 0, stream>>>(logits, (float*)d_out);
}

// Round 2
// 599.616 us; speedup vs baseline: 1.0686x; 1.0686x over previous
//
#include <hip/hip_runtime.h>

typedef unsigned short u16;
typedef float f32x4 __attribute__((ext_vector_type(4)));
typedef __bf16 bf16x8 __attribute__((ext_vector_type(8)));
typedef u16 u16x4 __attribute__((ext_vector_type(4)));
typedef u16 u16x8 __attribute__((ext_vector_type(8)));

__device__ __forceinline__ float bf2f(u16 u) {
    unsigned int x = ((unsigned int)u) << 16;
    return __builtin_bit_cast(float, x);
}
__device__ __forceinline__ u16 f2bf(float f) {
    unsigned int x = __builtin_bit_cast(unsigned int, f);
    x += 0x7fffu + ((x >> 16) & 1u);   // RNE
    return (u16)(x >> 16);
}

#define GLD16(gp, lp)                                                          \
    __builtin_amdgcn_global_load_lds(                                          \
        (const __attribute__((address_space(1))) void*)(gp),                   \
        (__attribute__((address_space(3))) void*)(lp), 16, 0, 0)

// ---------------------------------------------------------------------------
// prep kernels
// ---------------------------------------------------------------------------
__global__ void f32_to_bf16_k(const float* __restrict__ in, u16* __restrict__ out, long n4) {
    long i = (long)blockIdx.x * 256 + threadIdx.x;
    if (i >= n4) return;
    f32x4 v = *reinterpret_cast<const f32x4*>(in + i * 4);
    u16x4 o;
    o[0] = f2bf(v[0]); o[1] = f2bf(v[1]); o[2] = f2bf(v[2]); o[3] = f2bf(v[3]);
    *reinterpret_cast<u16x4*>(out + i * 4) = o;
}

// in fp32 [R][C] -> out bf16 [C][R]
__global__ void transpose_f32_bf16(const float* __restrict__ in, u16* __restrict__ out,
                                   int R, int C) {
    __shared__ float tile[32][33];
    const int bx = blockIdx.x * 32;
    const int by = blockIdx.y * 32;
    const int tx = threadIdx.x;
    const int ty0 = threadIdx.y;
    #pragma unroll
    for (int ty = ty0; ty < 32; ty += 8)
        tile[ty][tx] = in[(long)(by + ty) * C + bx + tx];
    __syncthreads();
    #pragma unroll
    for (int ty = ty0; ty < 32; ty += 8)
        out[(long)(bx + ty) * R + by + tx] = f2bf(tile[tx][ty]);
}

// H[B][32] = relu(P[B][8] @ W[8][32] + b), for all 4 hypernets in one pass
__global__ void hyper_h4(const float* __restrict__ P,
                         const float* __restrict__ Wa, const float* __restrict__ ba, u16* __restrict__ Ha,
                         const float* __restrict__ Wb, const float* __restrict__ bb_, u16* __restrict__ Hb,
                         const float* __restrict__ Wc, const float* __restrict__ bc, u16* __restrict__ Hc,
                         const float* __restrict__ Wd, const float* __restrict__ bd, u16* __restrict__ Hd,
                         int B_) {
    const int idx = blockIdx.x * 256 + threadIdx.x;
    if (idx >= B_ * 32) return;
    const int s = idx >> 5, c = idx & 31;
    float p[8];
    #pragma unroll
    for (int k = 0; k < 8; ++k) p[k] = P[s * 8 + k];
    auto one = [&](const float* W, const float* b, u16* H) {
        float a = b[c];
        #pragma unroll
        for (int k = 0; k < 8; ++k) a += p[k] * W[k * 32 + c];
        H[idx] = f2bf(fmaxf(a, 0.f));
    };
    one(Wa, ba, Ha); one(Wb, bb_, Hb); one(Wc, bc, Hc); one(Wd, bd, Hd);
}

// ---------------------------------------------------------------------------
// gemm256: C[M][N] = A[M][K] @ BT[N][K]^T + bias.
// 256x256 tile, BK=64, 512 thr / 8 waves (2M x 4N), 8-phase schedule,
// st_16x32 LDS swizzle (inverse-swz source + swz ds_read), counted vmcnt(4),
// setprio around MFMA, XCD-swizzled blockIdx.
// Wave (wr,wc): rows {wr*64..+63} u {128+wr*64..+63}, cols {wc*32..+31} u {128+wc*32..+31}
// -> each phase quadrant needs exactly one (A-half, B-half) pair.
// STATS: per-(col-block, wave-col) row partial sum/sumsq -> stats[(by*4+wc)][M][2]
// ---------------------------------------------------------------------------
template <int OUT_BF16, int STATS>
__global__ __launch_bounds__(512, 2) void gemm256(
    const u16* __restrict__ A, const u16* __restrict__ BT,
    const float* __restrict__ bias, u16* __restrict__ Cb, float* __restrict__ Cf,
    float* __restrict__ stats, int M, int N, int K, int mblocks) {
    __shared__ __align__(16) u16 lds[2][2][2][128 * 64];  // [buf][A0B1][half][8192]
    const int tid = threadIdx.x;
    const int lane = tid & 63;
    const int wave = tid >> 6;
    const int wr = wave & 1;
    const int wc = wave >> 1;

    // XCD swizzle (grid is a multiple of 8 here)
    const int nwg = gridDim.x;
    const int bid = blockIdx.x;
    const int swz = (bid & 7) * (nwg >> 3) + (bid >> 3);
    const int bx = swz % mblocks;
    const int by = swz / mblocks;
    const long row0 = (long)bx * 256;
    const long col0 = (long)by * 256;

    // staging: thread t covers LDS bytes [t*16, t*16+16) and +8192 of a half-tile
    const int srow = tid >> 3;                                   // 0..63
    const int scb = ((tid & 7) * 16) ^ (((tid >> 5) & 1) << 5);  // inverse-swz src col-byte
    const long sAoff = (row0 + srow) * (long)K + (scb >> 1);
    const long sBoff = (col0 + srow) * (long)K + (scb >> 1);

    auto STAGE = [&](int buf, int ab, int half, int kt) {
        const u16* g = (ab ? BT : A) + (ab ? sBoff : sAoff) + (long)half * 128 * K + (long)kt * 64;
        u16* d = &lds[buf][ab][half][tid * 8];
        GLD16(g, d);
        GLD16(g + 64 * (long)K, d + 4096);
    };

    // ds_read addressing (elements); swizzle bit depends only on lane
    const int ln15 = lane & 15, ln16 = lane >> 4;
    const int swz_b = ((ln15 >> 2) & 1) << 5;
    const int cbe0 = ((ln16 * 16) ^ swz_b) >> 1;   // kk=0; kk=1 adds 32
    const int arow = (wr * 64 + ln15) * 64;
    const int brow = (wc * 32 + ln15) * 64;

    f32x4 acc[8][4] = {};

#define PHASE(BUF, AH, BH, SAB, SH, KT)                                          \
    {                                                                            \
        asm volatile("s_waitcnt vmcnt(4)" ::: "memory");                         \
        __builtin_amdgcn_sched_barrier(0);                                       \
        __builtin_amdgcn_s_barrier();                                            \
        __builtin_amdgcn_sched_barrier(0);                                       \
        STAGE((BUF) ^ 1, SAB, SH, KT);                                           \
        bf16x8 aF[4][2], bF[2][2];                                               \
        const u16* ap = &lds[BUF][0][AH][0];                                     \
        const u16* bp = &lds[BUF][1][BH][0];                                     \
        _Pragma("unroll") for (int ml = 0; ml < 4; ++ml)                         \
            _Pragma("unroll") for (int kk = 0; kk < 2; ++kk)                     \
                aF[ml][kk] = *(const bf16x8*)(ap + arow + ml * 1024 + cbe0 + kk * 32); \
        _Pragma("unroll") for (int nl = 0; nl < 2; ++nl)                         \
            _Pragma("unroll") for (int kk = 0; kk < 2; ++kk)                     \
                bF[nl][kk] = *(const bf16x8*)(bp + brow + nl * 1024 + cbe0 + kk * 32); \
        __builtin_amdgcn_s_setprio(1);                                           \
        _Pragma("unroll") for (int ml = 0; ml < 4; ++ml)                         \
            _Pragma("unroll") for (int nl = 0; nl < 2; ++nl)                     \
                _Pragma("unroll") for (int kk = 0; kk < 2; ++kk)                 \
                    acc[(AH) * 4 + ml][(BH) * 2 + nl] =                          \
                        __builtin_amdgcn_mfma_f32_16x16x32_bf16(                 \
                            aF[ml][kk], bF[nl][kk], acc[(AH) * 4 + ml][(BH) * 2 + nl], 0, 0, 0); \
        __builtin_amdgcn_s_setprio(0);                                           \
    }

    // prologue: tile 0 halves in issue order Ah0, Bh0, Ah1, Bh1
    STAGE(0, 0, 0, 0); STAGE(0, 1, 0, 0); STAGE(0, 0, 1, 0); STAGE(0, 1, 1, 0);

    const int nt = K >> 6;
    for (int it = 0; it < (nt >> 1); ++it) {
        const int t0 = it * 2;
        const int ka = t0 + 1;
        const int kb = (t0 + 2 < nt) ? t0 + 2 : nt - 1;  // clamped redundant stage on last iter
        PHASE(0, 0, 0, 0, 0, ka)
        PHASE(0, 1, 0, 1, 0, ka)
        PHASE(0, 1, 1, 0, 1, ka)
        PHASE(0, 0, 1, 1, 1, ka)
        PHASE(1, 0, 0, 0, 0, kb)
        PHASE(1, 1, 0, 1, 0, kb)
        PHASE(1, 1, 1, 0, 1, kb)
        PHASE(1, 0, 1, 1, 1, kb)
    }
#undef PHASE
    asm volatile("s_waitcnt vmcnt(0)" ::: "memory");

    // epilogue
    float bv[4];
    #pragma unroll
    for (int n = 0; n < 4; ++n)
        bv[n] = bias[col0 + wc * 32 + (n & 1) * 16 + (n >> 1) * 128 + ln15];

    #pragma unroll
    for (int m = 0; m < 8; ++m) {
        const long rowb = row0 + wr * 64 + (m & 3) * 16 + (m >> 2) * 128 + ln16 * 4;
        #pragma unroll
        for (int n = 0; n < 4; ++n) {
            const long col = col0 + wc * 32 + (n & 1) * 16 + (n >> 1) * 128 + ln15;
            #pragma unroll
            for (int r = 0; r < 4; ++r) {
                const float v = acc[m][n][r] + bv[n];
                if (OUT_BF16) Cb[(rowb + r) * (long)N + col] = f2bf(v);
                else          Cf[(rowb + r) * (long)N + col] = v;
            }
        }
        if (STATS) {
            #pragma unroll
            for (int r = 0; r < 4; ++r) {
                float s = 0.f, ss = 0.f;
                #pragma unroll
                for (int n = 0; n < 4; ++n) {
                    const float v = acc[m][n][r] + bv[n];
                    s += v; ss += v * v;
                }
                #pragma unroll
                for (int d = 1; d < 16; d <<= 1) { s += __shfl_xor(s, d); ss += __shfl_xor(ss, d); }
                if (ln15 == 0) {
                    float* sp = stats + (((long)by * 4 + wc) * M + rowb + r) * 2;
                    sp[0] = s; sp[1] = ss;
                }
            }
        }
    }
}

// ---------------------------------------------------------------------------
// GroupNorm (n_group=1) + per-sample hypernet affine + ReLU, in place on Y.
// Stats come precomputed as NPART partials per row: stats[p][B][2].
// ---------------------------------------------------------------------------
template <int C, int NPART>
__global__ __launch_bounds__(256, 2) void gn_affine(
    u16* __restrict__ Y, const float* __restrict__ stats, int Btot,
    const u16* __restrict__ Hw, const u16* __restrict__ Hb,
    const u16* __restrict__ WwT, const u16* __restrict__ WbT,
    const float* __restrict__ bw, const float* __restrict__ bb) {
    const int tid = threadIdx.x;
    const int lane = tid & 63;
    const int wave = tid >> 6;
    const long r0 = (long)blockIdx.x * 32;
    __shared__ float mean_l[32], rs_l[32];
    __shared__ __align__(16) float wt[32][132];
    __shared__ __align__(16) float btl[32][132];

    const int row = tid >> 3, sub = tid & 7;

    // ---- stats from GEMM partials ----
    {
        float s = 0.f, ss = 0.f;
        for (int p_ = sub; p_ < NPART; p_ += 8) {
            const float* sp = stats + ((long)p_ * Btot + (r0 + row)) * 2;
            s += sp[0]; ss += sp[1];
        }
        s  += __shfl_xor(s, 1);  s  += __shfl_xor(s, 2);  s  += __shfl_xor(s, 4);
        ss += __shfl_xor(ss, 1); ss += __shfl_xor(ss, 2); ss += __shfl_xor(ss, 4);
        if (sub == 0) {
            float m = s / (float)C;
            float var = fmaxf(ss / (float)C - m * m, 0.f);
            mean_l[row] = m;
            rs_l[row] = rsqrtf(var + 1e-5f);
        }
    }
    __syncthreads();

    const int mm = wave & 1;
    const int npair = wave >> 1;
    const bf16x8 ha = *reinterpret_cast<const bf16x8*>(
        Hw + (r0 + mm * 16 + (lane & 15)) * 32 + (lane >> 4) * 8);
    const bf16x8 hbf = *reinterpret_cast<const bf16x8*>(
        Hb + (r0 + mm * 16 + (lane & 15)) * 32 + (lane >> 4) * 8);

    for (int c0 = 0; c0 < C; c0 += 128) {
        #pragma unroll
        for (int j = 0; j < 4; ++j) {
            const int n = npair * 4 + j;
            const int cl = c0 + n * 16 + (lane & 15);
            const bf16x8 wv = *reinterpret_cast<const bf16x8*>(WwT + (long)cl * 32 + (lane >> 4) * 8);
            const bf16x8 bv = *reinterpret_cast<const bf16x8*>(WbT + (long)cl * 32 + (lane >> 4) * 8);
            f32x4 z = {0.f, 0.f, 0.f, 0.f};
            f32x4 wa = __builtin_amdgcn_mfma_f32_16x16x32_bf16(ha, wv, z, 0, 0, 0);
            f32x4 ba = __builtin_amdgcn_mfma_f32_16x16x32_bf16(hbf, bv, z, 0, 0, 0);
            const float bwv = bw[cl], bbv = bb[cl];
            const int ncol = n * 16 + (lane & 15);
            #pragma unroll
            for (int r = 0; r < 4; ++r) {
                const int rl = mm * 16 + (lane >> 4) * 4 + r;
                wt[rl][ncol]  = wa[r] + bwv;
                btl[rl][ncol] = ba[r] + bbv;
            }
        }
        __syncthreads();
        {
            const long base = (r0 + row) * (long)C + c0 + sub * 16;
            u16x8 v0 = *reinterpret_cast<const u16x8*>(Y + base);
            u16x8 v1 = *reinterpret_cast<const u16x8*>(Y + base + 8);
            const float mu = mean_l[row], rs = rs_l[row];
            u16x8 o0, o1;
            #pragma unroll
            for (int j = 0; j < 8; ++j) {
                float f = (bf2f(v0[j]) - mu) * rs;
                f = f * wt[row][sub * 16 + j] + btl[row][sub * 16 + j];
                o0[j] = f2bf(fmaxf(f, 0.f));
                float g = (bf2f(v1[j]) - mu) * rs;
                g = g * wt[row][sub * 16 + 8 + j] + btl[row][sub * 16 + 8 + j];
                o1[j] = f2bf(fmaxf(g, 0.f));
            }
            *reinterpret_cast<u16x8*>(Y + base) = o0;
            *reinterpret_cast<u16x8*>(Y + base + 8) = o1;
        }
        __syncthreads();
    }
}

// ---------------------------------------------------------------------------
// GEMM3 (N=256): keep 128x128 kernel for occupancy (grid 512 blocks)
// ---------------------------------------------------------------------------
template <int OUT_BF16>
__global__ __launch_bounds__(256, 2) void gemm_bt(
    const u16* __restrict__ A, const u16* __restrict__ BT,
    const float* __restrict__ bias, u16* __restrict__ Cb, float* __restrict__ Cf,
    int M, int N, int K) {
    __shared__ __align__(16) u16 As[128 * 64];
    __shared__ __align__(16) u16 Bs[128 * 64];
    const int tid = threadIdx.x;
    const int lane = tid & 63;
    const int wave = tid >> 6;
    const int wr = wave >> 1, wc = wave & 1;
    const long row0 = (long)blockIdx.x * 128;
    const long col0 = (long)blockIdx.y * 128;

    const int srow = tid >> 3;
    const int scol = (tid & 7) * 8;
    const u16* Ag = A + (row0 + srow) * (long)K + scol;
    const u16* Bg = BT + (col0 + srow) * (long)K + scol;
    u16* AsW = As + (size_t)(wave * 64) * 8;
    u16* BsW = Bs + (size_t)(wave * 64) * 8;

    f32x4 acc[4][4] = {};

    for (int k0 = 0; k0 < K; k0 += 64) {
        #pragma unroll
        for (int i = 0; i < 4; ++i) {
            GLD16(Ag + (long)i * 32 * K + k0, AsW + i * 256 * 8);
            GLD16(Bg + (long)i * 32 * K + k0, BsW + i * 256 * 8);
        }
        __syncthreads();
        #pragma unroll
        for (int kk = 0; kk < 2; ++kk) {
            bf16x8 af[4], bfr[4];
            #pragma unroll
            for (int m = 0; m < 4; ++m)
                af[m] = *reinterpret_cast<const bf16x8*>(
                    As + (wr * 64 + m * 16 + (lane & 15)) * 64 + kk * 32 + (lane >> 4) * 8);
            #pragma unroll
            for (int n = 0; n < 4; ++n)
                bfr[n] = *reinterpret_cast<const bf16x8*>(
                    Bs + (wc * 64 + n * 16 + (lane & 15)) * 64 + kk * 32 + (lane >> 4) * 8);
            #pragma unroll
            for (int m = 0; m < 4; ++m)
                #pragma unroll
                for (int n = 0; n < 4; ++n)
                    acc[m][n] = __builtin_amdgcn_mfma_f32_16x16x32_bf16(af[m], bfr[n],
                                                                        acc[m][n], 0, 0, 0);
        }
        __syncthreads();
    }

    #pragma unroll
    for (int n = 0; n < 4; ++n) {
        const long col = col0 + wc * 64 + n * 16 + (lane & 15);
        const float bvv = bias[col];
        #pragma unroll
        for (int m = 0; m < 4; ++m) {
            const long rowb = row0 + wr * 64 + m * 16 + ((lane >> 4) * 4);
            #pragma unroll
            for (int r = 0; r < 4; ++r) {
                const float v = acc[m][n][r] + bvv;
                if (OUT_BF16) Cb[(rowb + r) * (long)N + col] = f2bf(v);
                else          Cf[(rowb + r) * (long)N + col] = v;
            }
        }
    }
}

// ---------------------------------------------------------------------------
// log_softmax over rows of 256, one wave per row
// ---------------------------------------------------------------------------
__global__ __launch_bounds__(256) void logsoftmax256(const float* __restrict__ X,
                                                     float* __restrict__ O) {
    const int wave = threadIdx.x >> 6, lane = threadIdx.x & 63;
    const long row = (long)blockIdx.x * 4 + wave;
    const float* x = X + row * 256 + lane * 4;
    f32x4 v = *reinterpret_cast<const f32x4*>(x);
    float mx = fmaxf(fmaxf(v[0], v[1]), fmaxf(v[2], v[3]));
    #pragma unroll
    for (int d = 1; d < 64; d <<= 1) mx = fmaxf(mx, __shfl_xor(mx, d));
    float s = 0.f;
    #pragma unroll
    for (int j = 0; j < 4; ++j) s += __expf(v[j] - mx);
    #pragma unroll
    for (int d = 1; d < 64; d <<= 1) s += __shfl_xor(s, d);
    const float lse = mx + logf(s);
    f32x4 o;
    #pragma unroll
    for (int j = 0; j < 4; ++j) o[j] = v[j] - lse;
    *reinterpret_cast<f32x4*>(O + row * 256 + lane * 4) = o;
}

// ---------------------------------------------------------------------------
extern "C" void kernel_launch(void* const* d_in, const int* in_sizes, int n_in,
                              void* d_out, int out_size, void* d_ws, size_t ws_size,
                              hipStream_t stream) {
    const float* x_feature = (const float*)d_in[0];
    const float* x_param   = (const float*)d_in[1];
    const float* hw1_1_w = (const float*)d_in[2];
    const float* hw1_1_b = (const float*)d_in[3];
    const float* hw1_2_w = (const float*)d_in[4];
    const float* hw1_2_b = (const float*)d_in[5];
    const float* hb1_1_w = (const float*)d_in[6];
    const float* hb1_1_b = (const float*)d_in[7];
    const float* hb1_2_w = (const float*)d_in[8];
    const float* hb1_2_b = (const float*)d_in[9];
    const float* hw2_1_w = (const float*)d_in[10];
    const float* hw2_1_b = (const float*)d_in[11];
    const float* hw2_2_w = (const float*)d_in[12];
    const float* hw2_2_b = (const float*)d_in[13];
    const float* hb2_1_w = (const float*)d_in[14];
    const float* hb2_1_b = (const float*)d_in[15];
    const float* hb2_2_w = (const float*)d_in[16];
    const float* hb2_2_b = (const float*)d_in[17];
    const float* l1_w = (const float*)d_in[18];
    const float* l1_b = (const float*)d_in[19];
    const float* l2_w = (const float*)d_in[20];
    const float* l2_b = (const float*)d_in[21];
    const float* l3_w = (const float*)d_in[22];
    const float* l3_b = (const float*)d_in[23];

    const int B = in_sizes[0] / 512;   // 32768
    constexpr int CIN = 512, C1 = 2048, C2 = 1024, COUT = 256;

    char* p = (char*)d_ws;
    auto carve = [&](size_t bytes) {
        char* q = p;
        p += (bytes + 255) & ~(size_t)255;
        return q;
    };
    u16* xb    = (u16*)carve((size_t)B * CIN * 2);
    u16* y1    = (u16*)carve((size_t)B * C1 * 2);
    u16* y2    = (u16*)carve((size_t)B * C2 * 2);
    u16* w1T   = (u16*)carve((size_t)C1 * CIN * 2);
    u16* w2T   = (u16*)carve((size_t)C2 * C1 * 2);
    u16* w3T   = (u16*)carve((size_t)COUT * C2 * 2);
    u16* hw12T = (u16*)carve((size_t)C1 * 32 * 2);
    u16* hb12T = (u16*)carve((size_t)C1 * 32 * 2);
    u16* hw22T = (u16*)carve((size_t)C2 * 32 * 2);
    u16* hb22T = (u16*)carve((size_t)C2 * 32 * 2);
    u16* Hw1   = (u16*)carve((size_t)B * 32 * 2);
    u16* Hb1   = (u16*)carve((size_t)B * 32 * 2);
    u16* Hw2   = (u16*)carve((size_t)B * 32 * 2);
    u16* Hb2   = (u16*)carve((size_t)B * 32 * 2);
    float* stat1 = (float*)carve((size_t)(C1 / 256) * 4 * B * 2 * 4);  // [32][B][2]
    float* stat2 = (float*)carve((size_t)(C2 / 256) * 4 * B * 2 * 4);  // [16][B][2]
    float* logits = (float*)y1;   // y1 dead once logits are written

    // ---- prep ----
    f32_to_bf16_k<<<(B * CIN / 4 + 255) / 256, 256, 0, stream>>>(x_feature, xb, (long)B * CIN / 4);
    dim3 tb(32, 8);
    transpose_f32_bf16<<<dim3(C1 / 32, CIN / 32), tb, 0, stream>>>(l1_w, w1T, CIN, C1);
    transpose_f32_bf16<<<dim3(C2 / 32, C1 / 32), tb, 0, stream>>>(l2_w, w2T, C1, C2);
    transpose_f32_bf16<<<dim3(COUT / 32, C2 / 32), tb, 0, stream>>>(l3_w, w3T, C2, COUT);
    transpose_f32_bf16<<<dim3(C1 / 32, 1), tb, 0, stream>>>(hw1_2_w, hw12T, 32, C1);
    transpose_f32_bf16<<<dim3(C1 / 32, 1), tb, 0, stream>>>(hb1_2_w, hb12T, 32, C1);
    transpose_f32_bf16<<<dim3(C2 / 32, 1), tb, 0, stream>>>(hw2_2_w, hw22T, 32, C2);
    transpose_f32_bf16<<<dim3(C2 / 32, 1), tb, 0, stream>>>(hb2_2_w, hb22T, 32, C2);
    hyper_h4<<<B * 32 / 256, 256, 0, stream>>>(x_param,
        hw1_1_w, hw1_1_b, Hw1, hb1_1_w, hb1_1_b, Hb1,
        hw2_1_w, hw2_1_b, Hw2, hb2_1_w, hb2_1_b, Hb2, B);

    // ---- main pipeline ----
    gemm256<1, 1><<<(B / 256) * (C1 / 256), 512, 0, stream>>>(
        xb, w1T, l1_b, y1, nullptr, stat1, B, C1, CIN, B / 256);
    gn_affine<C1, (C1 / 256) * 4><<<B / 32, 256, 0, stream>>>(
        y1, stat1, B, Hw1, Hb1, hw12T, hb12T, hw1_2_b, hb1_2_b);
    gemm256<1, 1><<<(B / 256) * (C2 / 256), 512, 0, stream>>>(
        y1, w2T, l2_b, y2, nullptr, stat2, B, C2, C1, B / 256);
    gn_affine<C2, (C2 / 256) * 4><<<B / 32, 256, 0, stream>>>(
        y2, stat2, B, Hw2, Hb2, hw22T, hb22T, hw2_2_b, hb2_2_b);
    gemm_bt<0><<<dim3(B / 128, COUT / 128), 256, 0, stream>>>(
        y2, w3T, l3_b, nullptr, logits, B, COUT, C2);
    logsoftmax256<<<B / 4, 256, 0, stream>>>(logits, (float*)d_out);
}

// Round 4
// 562.702 us; speedup vs baseline: 1.1388x; 1.0656x over previous
//
#include <hip/hip_runtime.h>

typedef unsigned short u16;
typedef float f32x4 __attribute__((ext_vector_type(4)));
typedef __bf16 bf16x8 __attribute__((ext_vector_type(8)));
typedef u16 u16x4 __attribute__((ext_vector_type(4)));
typedef u16 u16x8 __attribute__((ext_vector_type(8)));

__device__ __forceinline__ float bf2f(u16 u) {
    unsigned int x = ((unsigned int)u) << 16;
    return __builtin_bit_cast(float, x);
}
__device__ __forceinline__ u16 f2bf(float f) {
    unsigned int x = __builtin_bit_cast(unsigned int, f);
    x += 0x7fffu + ((x >> 16) & 1u);   // RNE
    return (u16)(x >> 16);
}

#define GLD16(gp, lp)                                                          \
    __builtin_amdgcn_global_load_lds(                                          \
        (const __attribute__((address_space(1))) void*)(gp),                   \
        (__attribute__((address_space(3))) void*)(lp), 16, 0, 0)

// ---------------------------------------------------------------------------
// prep kernels
// ---------------------------------------------------------------------------
__global__ void f32_to_bf16_k(const float* __restrict__ in, u16* __restrict__ out, long n4) {
    long i = (long)blockIdx.x * 256 + threadIdx.x;
    if (i >= n4) return;
    f32x4 v = *reinterpret_cast<const f32x4*>(in + i * 4);
    u16x4 o;
    o[0] = f2bf(v[0]); o[1] = f2bf(v[1]); o[2] = f2bf(v[2]); o[3] = f2bf(v[3]);
    *reinterpret_cast<u16x4*>(out + i * 4) = o;
}

// in fp32 [R][C] -> out bf16 [C][R]
__global__ void transpose_f32_bf16(const float* __restrict__ in, u16* __restrict__ out,
                                   int R, int C) {
    __shared__ float tile[32][33];
    const int bx = blockIdx.x * 32;
    const int by = blockIdx.y * 32;
    const int tx = threadIdx.x;
    const int ty0 = threadIdx.y;
    #pragma unroll
    for (int ty = ty0; ty < 32; ty += 8)
        tile[ty][tx] = in[(long)(by + ty) * C + bx + tx];
    __syncthreads();
    #pragma unroll
    for (int ty = ty0; ty < 32; ty += 8)
        out[(long)(bx + ty) * R + by + tx] = f2bf(tile[tx][ty]);
}

// H[B][32] = relu(P[B][8] @ W[8][32] + b), for all 4 hypernets in one pass
__global__ void hyper_h4(const float* __restrict__ P,
                         const float* __restrict__ Wa, const float* __restrict__ ba, u16* __restrict__ Ha,
                         const float* __restrict__ Wb, const float* __restrict__ bb_, u16* __restrict__ Hb,
                         const float* __restrict__ Wc, const float* __restrict__ bc, u16* __restrict__ Hc,
                         const float* __restrict__ Wd, const float* __restrict__ bd, u16* __restrict__ Hd,
                         int B_) {
    const int idx = blockIdx.x * 256 + threadIdx.x;
    if (idx >= B_ * 32) return;
    const int s = idx >> 5, c = idx & 31;
    float p[8];
    #pragma unroll
    for (int k = 0; k < 8; ++k) p[k] = P[s * 8 + k];
    auto one = [&](const float* W, const float* b, u16* H) {
        float a = b[c];
        #pragma unroll
        for (int k = 0; k < 8; ++k) a += p[k] * W[k * 32 + c];
        H[idx] = f2bf(fmaxf(a, 0.f));
    };
    one(Wa, ba, Ha); one(Wb, bb_, Hb); one(Wc, bc, Hc); one(Wd, bd, Hd);
}

// ---------------------------------------------------------------------------
// gemm256: C[M][N] = A[M][K] @ BT[N][K]^T + bias.
// 256x256 tile, BK=64, 512 thr / 8 waves (2M x 4N), 8-phase counted-vmcnt
// schedule, 3-bit XOR LDS swizzle (slot ^= row&7; inverse-swz source, swz
// ds_read), setprio around MFMA, XCD-swizzled blockIdx.
// STATS: per-(col-block,wave-col) row partials -> stats[(by*4+wc)][M][2]
// LSM:   N==256, one col-block: fused log-softmax epilogue, fp32 out to Cf.
// ---------------------------------------------------------------------------
template <int OUT_BF16, int STATS, int LSM>
__global__ __launch_bounds__(512, 2) void gemm256(
    const u16* __restrict__ A, const u16* __restrict__ BT,
    const float* __restrict__ bias, u16* __restrict__ Cb, float* __restrict__ Cf,
    float* __restrict__ stats, int M, int N, int K, int mblocks) {
    __shared__ __align__(16) u16 lds[2][2][2][128 * 64];  // [buf][A0B1][half][8192]
    const int tid = threadIdx.x;
    const int lane = tid & 63;
    const int wave = tid >> 6;
    const int wr = wave & 1;
    const int wc = wave >> 1;

    // XCD swizzle (grid is a multiple of 8 here)
    const int nwg = gridDim.x;
    const int bid = blockIdx.x;
    const int swz = (bid & 7) * (nwg >> 3) + (bid >> 3);
    const int bx = swz % mblocks;
    const int by = swz / mblocks;
    const long row0 = (long)bx * 256;
    const long col0 = (long)by * 256;

    // staging: thread t writes LDS bytes [t*16,t*16+16) (linear dest);
    // source 16B-slot pre-XORed with (row&7) so LDS[row][slot]=G[row][slot^(row&7)]
    const int srow = tid >> 3;                                  // 0..63
    const int selem = (((tid & 7) ^ ((tid >> 3) & 7)) << 3);    // source col element
    const long sAoff = (row0 + srow) * (long)K + selem;
    const long sBoff = (col0 + srow) * (long)K + selem;

    auto STAGE = [&](int buf, int ab, int half, int kt) {
        const u16* g = (ab ? BT : A) + (ab ? sBoff : sAoff) + (long)half * 128 * K + (long)kt * 64;
        u16* d = &lds[buf][ab][half][tid * 8];
        GLD16(g, d);
        GLD16(g + 64 * (long)K, d + 4096);
    };

    // ds_read addressing: row-in-half = (.. + ln15), col slot = (ln16+4kk)^(ln15&7)
    const int ln15 = lane & 15, ln16 = lane >> 4;
    const int c0e = ((ln16)     ^ (ln15 & 7)) << 3;   // kk=0 col element
    const int c1e = ((ln16 + 4) ^ (ln15 & 7)) << 3;   // kk=1 col element
    const int arow = (wr * 64 + ln15) * 64;
    const int brow = (wc * 32 + ln15) * 64;

    f32x4 acc[8][4] = {};

#define PHASE(BUF, AH, BH, SAB, SH, KT)                                          \
    {                                                                            \
        asm volatile("s_waitcnt vmcnt(4)" ::: "memory");                         \
        __builtin_amdgcn_sched_barrier(0);                                       \
        __builtin_amdgcn_s_barrier();                                            \
        __builtin_amdgcn_sched_barrier(0);                                       \
        STAGE((BUF) ^ 1, SAB, SH, KT);                                           \
        bf16x8 aF[4][2], bF[2][2];                                               \
        const u16* ap = &lds[BUF][0][AH][0];                                     \
        const u16* bp = &lds[BUF][1][BH][0];                                     \
        _Pragma("unroll") for (int ml = 0; ml < 4; ++ml) {                       \
            aF[ml][0] = *(const bf16x8*)(ap + arow + ml * 1024 + c0e);           \
            aF[ml][1] = *(const bf16x8*)(ap + arow + ml * 1024 + c1e);           \
        }                                                                        \
        _Pragma("unroll") for (int nl = 0; nl < 2; ++nl) {                       \
            bF[nl][0] = *(const bf16x8*)(bp + brow + nl * 1024 + c0e);           \
            bF[nl][1] = *(const bf16x8*)(bp + brow + nl * 1024 + c1e);           \
        }                                                                        \
        __builtin_amdgcn_s_setprio(1);                                           \
        _Pragma("unroll") for (int ml = 0; ml < 4; ++ml)                         \
            _Pragma("unroll") for (int nl = 0; nl < 2; ++nl)                     \
                _Pragma("unroll") for (int kk = 0; kk < 2; ++kk)                 \
                    acc[(AH) * 4 + ml][(BH) * 2 + nl] =                          \
                        __builtin_amdgcn_mfma_f32_16x16x32_bf16(                 \
                            aF[ml][kk], bF[nl][kk], acc[(AH) * 4 + ml][(BH) * 2 + nl], 0, 0, 0); \
        __builtin_amdgcn_s_setprio(0);                                           \
    }

    // prologue: tile 0 halves in issue order Ah0, Bh0, Ah1, Bh1
    STAGE(0, 0, 0, 0); STAGE(0, 1, 0, 0); STAGE(0, 0, 1, 0); STAGE(0, 1, 1, 0);

    const int nt = K >> 6;
    for (int it = 0; it < (nt >> 1); ++it) {
        const int t0 = it * 2;
        const int ka = t0 + 1;
        const int kb = (t0 + 2 < nt) ? t0 + 2 : nt - 1;  // clamped redundant stage on last iter
        PHASE(0, 0, 0, 0, 0, ka)
        PHASE(0, 1, 0, 1, 0, ka)
        PHASE(0, 1, 1, 0, 1, ka)
        PHASE(0, 0, 1, 1, 1, ka)
        PHASE(1, 0, 0, 0, 0, kb)
        PHASE(1, 1, 0, 1, 0, kb)
        PHASE(1, 1, 1, 0, 1, kb)
        PHASE(1, 0, 1, 1, 1, kb)
    }
#undef PHASE
    asm volatile("s_waitcnt vmcnt(0)" ::: "memory");

    float bv[4];
    #pragma unroll
    for (int n = 0; n < 4; ++n)
        bv[n] = bias[col0 + wc * 32 + (n & 1) * 16 + (n >> 1) * 128 + ln15];

    if constexpr (LSM) {
        // all DMA drained in every wave before LDS reuse
        __syncthreads();
        float* red  = (float*)&lds[0][0][0][0];   // [4][256]
        float* red2 = red + 1024;                 // [4][256]
        #pragma unroll
        for (int m = 0; m < 8; ++m)
            #pragma unroll
            for (int n = 0; n < 4; ++n)
                #pragma unroll
                for (int r = 0; r < 4; ++r)
                    acc[m][n][r] += bv[n];
        // pass 1: per-wc row max
        #pragma unroll
        for (int m = 0; m < 8; ++m) {
            const int rb = wr * 64 + (m & 3) * 16 + (m >> 2) * 128 + ln16 * 4;
            #pragma unroll
            for (int r = 0; r < 4; ++r) {
                float mx = fmaxf(fmaxf(acc[m][0][r], acc[m][1][r]),
                                 fmaxf(acc[m][2][r], acc[m][3][r]));
                #pragma unroll
                for (int d = 1; d < 16; d <<= 1) mx = fmaxf(mx, __shfl_xor(mx, d));
                if (ln15 == 0) red[wc * 256 + rb + r] = mx;
            }
        }
        __syncthreads();
        float gmv[8][4];
        #pragma unroll
        for (int m = 0; m < 8; ++m) {
            const int rb = wr * 64 + (m & 3) * 16 + (m >> 2) * 128 + ln16 * 4;
            #pragma unroll
            for (int r = 0; r < 4; ++r) {
                float gm = fmaxf(fmaxf(red[rb + r], red[256 + rb + r]),
                                 fmaxf(red[512 + rb + r], red[768 + rb + r]));
                float se = 0.f;
                #pragma unroll
                for (int n = 0; n < 4; ++n) se += __expf(acc[m][n][r] - gm);
                #pragma unroll
                for (int d = 1; d < 16; d <<= 1) se += __shfl_xor(se, d);
                if (ln15 == 0) red2[wc * 256 + rb + r] = se;
                gmv[m][r] = gm;
            }
        }
        __syncthreads();
        #pragma unroll
        for (int m = 0; m < 8; ++m) {
            const int rb = wr * 64 + (m & 3) * 16 + (m >> 2) * 128 + ln16 * 4;
            const long rowb = row0 + rb;
            #pragma unroll
            for (int r = 0; r < 4; ++r) {
                const float gs = red2[rb + r] + red2[256 + rb + r] +
                                 red2[512 + rb + r] + red2[768 + rb + r];
                const float l = gmv[m][r] + __logf(gs);
                #pragma unroll
                for (int n = 0; n < 4; ++n) {
                    const long col = wc * 32 + (n & 1) * 16 + (n >> 1) * 128 + ln15;
                    Cf[(rowb + r) * (long)N + col] = acc[m][n][r] - l;
                }
            }
        }
        return;
    }

    #pragma unroll
    for (int m = 0; m < 8; ++m) {
        const long rowb = row0 + wr * 64 + (m & 3) * 16 + (m >> 2) * 128 + ln16 * 4;
        #pragma unroll
        for (int n = 0; n < 4; ++n) {
            const long col = col0 + wc * 32 + (n & 1) * 16 + (n >> 1) * 128 + ln15;
            #pragma unroll
            for (int r = 0; r < 4; ++r) {
                const float v = acc[m][n][r] + bv[n];
                if (OUT_BF16) Cb[(rowb + r) * (long)N + col] = f2bf(v);
                else          Cf[(rowb + r) * (long)N + col] = v;
            }
        }
        if (STATS) {
            #pragma unroll
            for (int r = 0; r < 4; ++r) {
                float s = 0.f, ss = 0.f;
                #pragma unroll
                for (int n = 0; n < 4; ++n) {
                    const float v = acc[m][n][r] + bv[n];
                    s += v; ss += v * v;
                }
                #pragma unroll
                for (int d = 1; d < 16; d <<= 1) { s += __shfl_xor(s, d); ss += __shfl_xor(ss, d); }
                if (ln15 == 0) {
                    float* sp = stats + (((long)by * 4 + wc) * M + rowb + r) * 2;
                    sp[0] = s; sp[1] = ss;
                }
            }
        }
    }
}

// ---------------------------------------------------------------------------
// GroupNorm (n_group=1) + per-sample hypernet affine + ReLU, in place on Y.
// Stats come precomputed as NPART partials per row: stats[p][B][2].
// ---------------------------------------------------------------------------
template <int C, int NPART>
__global__ __launch_bounds__(256, 2) void gn_affine(
    u16* __restrict__ Y, const float* __restrict__ stats, int Btot,
    const u16* __restrict__ Hw, const u16* __restrict__ Hb,
    const u16* __restrict__ WwT, const u16* __restrict__ WbT,
    const float* __restrict__ bw, const float* __restrict__ bb) {
    const int tid = threadIdx.x;
    const int lane = tid & 63;
    const int wave = tid >> 6;
    const long r0 = (long)blockIdx.x * 32;
    __shared__ float mean_l[32], rs_l[32];
    __shared__ __align__(16) float wt[32][132];
    __shared__ __align__(16) float btl[32][132];

    const int row = tid >> 3, sub = tid & 7;

    // ---- stats from GEMM partials ----
    {
        float s = 0.f, ss = 0.f;
        for (int p_ = sub; p_ < NPART; p_ += 8) {
            const float* sp = stats + ((long)p_ * Btot + (r0 + row)) * 2;
            s += sp[0]; ss += sp[1];
        }
        s  += __shfl_xor(s, 1);  s  += __shfl_xor(s, 2);  s  += __shfl_xor(s, 4);
        ss += __shfl_xor(ss, 1); ss += __shfl_xor(ss, 2); ss += __shfl_xor(ss, 4);
        if (sub == 0) {
            float m = s / (float)C;
            float var = fmaxf(ss / (float)C - m * m, 0.f);
            mean_l[row] = m;
            rs_l[row] = rsqrtf(var + 1e-5f);
        }
    }
    __syncthreads();

    const int mm = wave & 1;
    const int npair = wave >> 1;
    const bf16x8 ha = *reinterpret_cast<const bf16x8*>(
        Hw + (r0 + mm * 16 + (lane & 15)) * 32 + (lane >> 4) * 8);
    const bf16x8 hbf = *reinterpret_cast<const bf16x8*>(
        Hb + (r0 + mm * 16 + (lane & 15)) * 32 + (lane >> 4) * 8);

    for (int c0 = 0; c0 < C; c0 += 128) {
        #pragma unroll
        for (int j = 0; j < 4; ++j) {
            const int n = npair * 4 + j;
            const int cl = c0 + n * 16 + (lane & 15);
            const bf16x8 wv = *reinterpret_cast<const bf16x8*>(WwT + (long)cl * 32 + (lane >> 4) * 8);
            const bf16x8 bv = *reinterpret_cast<const bf16x8*>(WbT + (long)cl * 32 + (lane >> 4) * 8);
            f32x4 z = {0.f, 0.f, 0.f, 0.f};
            f32x4 wa = __builtin_amdgcn_mfma_f32_16x16x32_bf16(ha, wv, z, 0, 0, 0);
            f32x4 ba = __builtin_amdgcn_mfma_f32_16x16x32_bf16(hbf, bv, z, 0, 0, 0);
            const float bwv = bw[cl], bbv = bb[cl];
            const int ncol = n * 16 + (lane & 15);
            #pragma unroll
            for (int r = 0; r < 4; ++r) {
                const int rl = mm * 16 + (lane >> 4) * 4 + r;
                wt[rl][ncol]  = wa[r] + bwv;
                btl[rl][ncol] = ba[r] + bbv;
            }
        }
        __syncthreads();
        {
            const long base = (r0 + row) * (long)C + c0 + sub * 16;
            u16x8 v0 = *reinterpret_cast<const u16x8*>(Y + base);
            u16x8 v1 = *reinterpret_cast<const u16x8*>(Y + base + 8);
            const float mu = mean_l[row], rs = rs_l[row];
            u16x8 o0, o1;
            #pragma unroll
            for (int j = 0; j < 8; ++j) {
                float f = (bf2f(v0[j]) - mu) * rs;
                f = f * wt[row][sub * 16 + j] + btl[row][sub * 16 + j];
                o0[j] = f2bf(fmaxf(f, 0.f));
                float g = (bf2f(v1[j]) - mu) * rs;
                g = g * wt[row][sub * 16 + 8 + j] + btl[row][sub * 16 + 8 + j];
                o1[j] = f2bf(fmaxf(g, 0.f));
            }
            *reinterpret_cast<u16x8*>(Y + base) = o0;
            *reinterpret_cast<u16x8*>(Y + base + 8) = o1;
        }
        __syncthreads();
    }
}

// ---------------------------------------------------------------------------
extern "C" void kernel_launch(void* const* d_in, const int* in_sizes, int n_in,
                              void* d_out, int out_size, void* d_ws, size_t ws_size,
                              hipStream_t stream) {
    const float* x_feature = (const float*)d_in[0];
    const float* x_param   = (const float*)d_in[1];
    const float* hw1_1_w = (const float*)d_in[2];
    const float* hw1_1_b = (const float*)d_in[3];
    const float* hw1_2_w = (const float*)d_in[4];
    const float* hw1_2_b = (const float*)d_in[5];
    const float* hb1_1_w = (const float*)d_in[6];
    const float* hb1_1_b = (const float*)d_in[7];
    const float* hb1_2_w = (const float*)d_in[8];
    const float* hb1_2_b = (const float*)d_in[9];
    const float* hw2_1_w = (const float*)d_in[10];
    const float* hw2_1_b = (const float*)d_in[11];
    const float* hw2_2_w = (const float*)d_in[12];
    const float* hw2_2_b = (const float*)d_in[13];
    const float* hb2_1_w = (const float*)d_in[14];
    const float* hb2_1_b = (const float*)d_in[15];
    const float* hb2_2_w = (const float*)d_in[16];
    const float* hb2_2_b = (const float*)d_in[17];
    const float* l1_w = (const float*)d_in[18];
    const float* l1_b = (const float*)d_in[19];
    const float* l2_w = (const float*)d_in[20];
    const float* l2_b = (const float*)d_in[21];
    const float* l3_w = (const float*)d_in[22];
    const float* l3_b = (const float*)d_in[23];

    const int B = in_sizes[0] / 512;   // 32768
    constexpr int CIN = 512, C1 = 2048, C2 = 1024, COUT = 256;

    char* p = (char*)d_ws;
    auto carve = [&](size_t bytes) {
        char* q = p;
        p += (bytes + 255) & ~(size_t)255;
        return q;
    };
    u16* xb    = (u16*)carve((size_t)B * CIN * 2);
    u16* y1    = (u16*)carve((size_t)B * C1 * 2);
    u16* y2    = (u16*)carve((size_t)B * C2 * 2);
    u16* w1T   = (u16*)carve((size_t)C1 * CIN * 2);
    u16* w2T   = (u16*)carve((size_t)C2 * C1 * 2);
    u16* w3T   = (u16*)carve((size_t)COUT * C2 * 2);
    u16* hw12T = (u16*)carve((size_t)C1 * 32 * 2);
    u16* hb12T = (u16*)carve((size_t)C1 * 32 * 2);
    u16* hw22T = (u16*)carve((size_t)C2 * 32 * 2);
    u16* hb22T = (u16*)carve((size_t)C2 * 32 * 2);
    u16* Hw1   = (u16*)carve((size_t)B * 32 * 2);
    u16* Hb1   = (u16*)carve((size_t)B * 32 * 2);
    u16* Hw2   = (u16*)carve((size_t)B * 32 * 2);
    u16* Hb2   = (u16*)carve((size_t)B * 32 * 2);
    float* stat1 = (float*)carve((size_t)(C1 / 256) * 4 * B * 2 * 4);  // [32][B][2]
    float* stat2 = (float*)carve((size_t)(C2 / 256) * 4 * B * 2 * 4);  // [16][B][2]

    // ---- prep ----
    f32_to_bf16_k<<<(B * CIN / 4 + 255) / 256, 256, 0, stream>>>(x_feature, xb, (long)B * CIN / 4);
    dim3 tb(32, 8);
    transpose_f32_bf16<<<dim3(C1 / 32, CIN / 32), tb, 0, stream>>>(l1_w, w1T, CIN, C1);
    transpose_f32_bf16<<<dim3(C2 / 32, C1 / 32), tb, 0, stream>>>(l2_w, w2T, C1, C2);
    transpose_f32_bf16<<<dim3(COUT / 32, C2 / 32), tb, 0, stream>>>(l3_w, w3T, C2, COUT);
    transpose_f32_bf16<<<dim3(C1 / 32, 1), tb, 0, stream>>>(hw1_2_w, hw12T, 32, C1);
    transpose_f32_bf16<<<dim3(C1 / 32, 1), tb, 0, stream>>>(hb1_2_w, hb12T, 32, C1);
    transpose_f32_bf16<<<dim3(C2 / 32, 1), tb, 0, stream>>>(hw2_2_w, hw22T, 32, C2);
    transpose_f32_bf16<<<dim3(C2 / 32, 1), tb, 0, stream>>>(hb2_2_w, hb22T, 32, C2);
    hyper_h4<<<B * 32 / 256, 256, 0, stream>>>(x_param,
        hw1_1_w, hw1_1_b, Hw1, hb1_1_w, hb1_1_b, Hb1,
        hw2_1_w, hw2_1_b, Hw2, hb2_1_w, hb2_1_b, Hb2, B);

    // ---- main pipeline ----
    gemm256<1, 1, 0><<<(B / 256) * (C1 / 256), 512, 0, stream>>>(
        xb, w1T, l1_b, y1, nullptr, stat1, B, C1, CIN, B / 256);
    gn_affine<C1, (C1 / 256) * 4><<<B / 32, 256, 0, stream>>>(
        y1, stat1, B, Hw1, Hb1, hw12T, hb12T, hw1_2_b, hb1_2_b);
    gemm256<1, 1, 0><<<(B / 256) * (C2 / 256), 512, 0, stream>>>(
        y1, w2T, l2_b, y2, nullptr, stat2, B, C2, C1, B / 256);
    gn_affine<C2, (C2 / 256) * 4><<<B / 32, 256, 0, stream>>>(
        y2, stat2, B, Hw2, Hb2, hw22T, hb22T, hw2_2_b, hb2_2_b);
    gemm256<0, 0, 1><<<(B / 256) * (COUT / 256), 512, 0, stream>>>(
        y2, w3T, l3_b, nullptr, (float*)d_out, nullptr, B, COUT, C2, B / 256);
}